// Round 6
// baseline (29642.444 us; speedup 1.0000x reference)
//
#include <hip/hip_runtime.h>
#include <hip/hip_fp16.h>

constexpr int kB = 128;
constexpr int kN = 1000;
constexpr int kE = 128;
constexpr int kH = 8;
constexpr float kFP8Scale = 64.f;         // fp8 values stored as v*64
constexpr float kQKScale = 0.25f / 64.f;  // 1/sqrt(16) folded with 1/64
constexpr int kPP = 1028;                 // padded p row stride (floats)
constexpr int kPS = 132;                  // parts row stride (floats)

typedef _Float16 h2 __attribute__((ext_vector_type(2)));
typedef float f2 __attribute__((ext_vector_type(2)));

__device__ __forceinline__ h2 pkrtz(float a, float b) {
  return __builtin_bit_cast(h2, __builtin_amdgcn_cvt_pkrtz(a, b));
}

// dot of 4 fp8 elems (packed in u, stored value*64) against 4 f16 elems.
__device__ __forceinline__ float dotq(unsigned u, h2 qa, h2 qb, float s) {
  f2 lo = __builtin_amdgcn_cvt_pk_f32_fp8(u, false);
  f2 hi = __builtin_amdgcn_cvt_pk_f32_fp8(u, true);
  h2 l16 = pkrtz(lo.x, lo.y);
  h2 h16 = pkrtz(hi.x, hi.y);
  s = __builtin_amdgcn_fdot2(l16, qa, s, false);
  s = __builtin_amdgcn_fdot2(h16, qb, s, false);
  return s;
}
// 16-elem fp8 dot (one uint4) against 16 f16 elems in q8[0..7].
__device__ __forceinline__ float dot16(uint4 tq, const h2* q8, float s) {
  s = dotq(tq.x, q8[0], q8[1], s);
  s = dotq(tq.y, q8[2], q8[3], s);
  s = dotq(tq.z, q8[4], q8[5], s);
  s = dotq(tq.w, q8[6], q8[7], s);
  return s;
}

__device__ __forceinline__ float fast_tanh(float x) {
  float t = __expf(2.f * x);
  return 1.f - 2.f / (t + 1.f);
}

__device__ __forceinline__ unsigned char enc_fp8(float v) {
  unsigned p = __builtin_amdgcn_cvt_pk_fp8_f32(v, v, 0, false);
  return (unsigned char)(p & 0xFF);
}

// online-softmax / argmax combine; tie -> smaller node id (jnp.argmax).
__device__ __forceinline__ void combine(float& m, float& s, int& a,
                                        float mo, float so, int ao) {
  bool take = (mo > m) || (mo == m && ao < a);
  float mw = take ? mo : m;
  float ml = take ? m : mo;
  float sw = take ? so : s;
  float sl = take ? s : so;
  s = sw + sl * __expf(ml - mw);
  m = mw;
  a = take ? ao : a;
}

// ---- DPP cross-lane helpers (VALU pipe, not DS) ---------------------------
template <int CTRL>
__device__ __forceinline__ float dpp_bcastf(float x) {
  return __builtin_bit_cast(
      float, __builtin_amdgcn_update_dpp(0, __builtin_bit_cast(int, x), CTRL,
                                         0xf, 0xf, true));
}
template <int CTRL>
__device__ __forceinline__ int dpp_bcasti(int x) {
  return __builtin_amdgcn_update_dpp(0, x, CTRL, 0xf, 0xf, true);
}
template <int CTRL>
__device__ __forceinline__ float dpp_addf(float x) {
  return x + dpp_bcastf<CTRL>(x);
}
template <int CTRL>
__device__ __forceinline__ void dpp_combine(float& m, float& s, int& a) {
  float mo = dpp_bcastf<CTRL>(m);
  float so = dpp_bcastf<CTRL>(s);
  int ao = dpp_bcasti<CTRL>(a);
  combine(m, s, a, mo, so, ao);
}

// LDS-only barrier: drains DS ops, leaves global register-loads in flight.
__device__ __forceinline__ void barrier_lds() {
  asm volatile("s_waitcnt lgkmcnt(0)" ::: "memory");
  __builtin_amdgcn_s_barrier();
  asm volatile("" ::: "memory");
}

// ---------------------------------------------------------------------------
// Kernel A: qkv projection -> fp8 (value*64) k / v / logit_k.
// ---------------------------------------------------------------------------
__global__ __launch_bounds__(384) void qkv_kernel(
    const float* __restrict__ ne, const float* __restrict__ Wqkv,
    const float* __restrict__ bqkv, unsigned char* __restrict__ kq,
    unsigned char* __restrict__ vq, unsigned char* __restrict__ lkq) {
  __shared__ float rows[16 * kE];
  int b = blockIdx.x;
  int n0 = blockIdx.y * 16;
  int ntile = min(16, kN - n0);
  int tid = threadIdx.x;

  for (int idx = tid; idx < ntile * kE; idx += 384)
    rows[idx] = ne[(b * kN + n0) * kE + idx];
  __syncthreads();

  int j = tid;  // 0..383
  float acc[16];
#pragma unroll
  for (int r = 0; r < 16; ++r) acc[r] = 0.f;
  for (int i = 0; i < kE; ++i) {
    float w = Wqkv[i * (3 * kE) + j];
#pragma unroll
    for (int r = 0; r < 16; ++r) acc[r] += rows[r * kE + i] * w;
  }
  float bias = bqkv[j];
  unsigned char* dst;
  int col;
  if (j < kE) { dst = kq; col = j; }
  else if (j < 2 * kE) { dst = vq; col = j - kE; }
  else { dst = lkq; col = j - 2 * kE; }
  for (int r = 0; r < ntile; ++r)
    dst[(size_t)(b * kN + n0 + r) * kE + col] =
        enc_fp8((acc[r] + bias) * kFP8Scale);
}

// ---------------------------------------------------------------------------
// Kernel B: qbase[b] = ge@Wfix + bfix + first@Wstep_top + bstep  (fp32)
// ---------------------------------------------------------------------------
__global__ __launch_bounds__(128) void qbase_kernel(
    const float* __restrict__ ne, const float* __restrict__ ge,
    const float* __restrict__ Wfix, const float* __restrict__ bfix,
    const float* __restrict__ Wstep, const float* __restrict__ bstep,
    float* __restrict__ qbase) {
  __shared__ float g[kE], f[kE];
  int b = blockIdx.x, e = threadIdx.x;
  g[e] = ge[b * kE + e];
  f[e] = ne[(size_t)b * kN * kE + e];  // node 0
  __syncthreads();
  float acc = bfix[e] + bstep[e];
  for (int i = 0; i < kE; ++i)
    acc += g[i] * Wfix[i * kE + e] + f[i] * Wstep[i * kE + e];
  qbase[b * kE + e] = acc;
}

// ---------------------------------------------------------------------------
// Kernel B2: qstep[b,n] = (qbase[b] + ne[b,n] @ Wbot) * kQKScale, f16.
// ---------------------------------------------------------------------------
__global__ __launch_bounds__(128) void qstep_kernel(
    const float* __restrict__ ne, const float* __restrict__ Wstep,
    const float* __restrict__ qbase, __half* __restrict__ qstep) {
  __shared__ float rows[8 * kE];
  int b = blockIdx.x;
  int n0 = blockIdx.y * 8;
  int tid = threadIdx.x;
  const float* Wbot = Wstep + kE * kE;

  for (int idx = tid; idx < 8 * kE; idx += 128)
    rows[idx] = ne[((size_t)b * kN + n0) * kE + idx];
  __syncthreads();

  float acc[8];
#pragma unroll
  for (int r = 0; r < 8; ++r) acc[r] = 0.f;
  for (int i = 0; i < kE; ++i) {
    float w = Wbot[i * kE + tid];
#pragma unroll
    for (int r = 0; r < 8; ++r) acc[r] += rows[r * kE + i] * w;
  }
  float qb = qbase[b * kE + tid];
#pragma unroll
  for (int r = 0; r < 8; ++r)
    qstep[((size_t)b * kN + n0 + r) * kE + tid] =
        __float2half((qb + acc[r]) * kQKScale);
}

// ---------------------------------------------------------------------------
// Kernel C: 999-step rollout, one 1024-thread block per batch element.
// STATIC STREAMING structure:
//  * slot -> node is IDENTITY (j = g + 128r, fixed forever). Liveness is an
//    8-bit per-thread REGISTER mask; dead nodes get p=0 (contribute exactly
//    +0.0 to ctx/den).  No rem[], no pos[], no indirection anywhere.
//  * every K/V/LK address is loop-invariant -> hoisted, zero per-step
//    address VALU, no LDS-read-before-VMEM dependency.
//  * phase 2 is branchless (p=0 masks dead rows); depth-4 V pipeline.
//  * no end-of-step barrier (nothing in LDS mutates at step end):
//    5 barriers/step.
// ---------------------------------------------------------------------------
__global__ __launch_bounds__(1024) void rollout_kernel(
    const float* __restrict__ Wmlp, const float* __restrict__ bmlp,
    const unsigned char* __restrict__ kq, const unsigned char* __restrict__ vq,
    const unsigned char* __restrict__ lkq, const __half* __restrict__ qstep,
    float* __restrict__ out) {
  __shared__ __align__(16) float p[kH][kPP];       // exp(scores), 32.9 KB
  __shared__ __align__(16) float parts[32 * kPS];  // ctx partials, 16.9 KB
  __shared__ float bm[kE];
  __shared__ __align__(16) float ctx[kE];
  __shared__ __align__(16) __half xh[kE];
  __shared__ float redSum[16][kH];
  __shared__ __align__(16) float4 redPack[16];  // (m, ssum, argbits, -)

  int b = blockIdx.x;
  int tid = threadIdx.x;
  int lane = tid & 63;
  int wave = tid >> 6;
  int g = tid >> 3;    // node-group 0..127; owns nodes j = g + 128r
  int t = tid & 7;     // head / uint4 slot within row
  int w2 = tid >> 5;   // half-wave 0..31; owns V rows w2*4+128q+k
  int idx = tid & 31;  // uint index within a 128B row
  int h = idx >> 2;    // head owning elems 4*idx..4*idx+3

  const unsigned char* kqb = kq + (size_t)b * kN * kE;
  const unsigned char* vqb = vq + (size_t)b * kN * kE;
  const unsigned char* lqb = lkq + (size_t)b * kN * kE;
  const __half* qsb = qstep + (size_t)b * kN * kE;

  // x-matvec weight column (output elem g, i-chunk t), register resident
  float wm[16];
#pragma unroll
  for (int i = 0; i < 16; ++i) wm[i] = Wmlp[(t * 16 + i) * kE + g];

  if (tid < kE) bm[tid] = bmlp[tid];

  // liveness mask: bit r <=> node g+128r live.  node 0 pre-visited;
  // slots with j > 999 (g>103, r=7) permanently dead.
  unsigned alive = 0xFFu;
  if (g == 0) alive &= 0xFEu;
  if (g > 103) alive &= 0x7Fu;

  // clamped row ids (memory-safe for the dead >999 slots) — loop-invariant
  int jc[8];
#pragma unroll
  for (int r = 0; r < 8; ++r) {
    int j = g + 128 * r;
    jc[r] = (j <= 999) ? j : 0;
  }

  // current action + its q row (prefetched into registers; node 0 first)
  int A = 0;
  uint4 qa, qb_;
  {
    const uint4* qr = (const uint4*)qsb;
    qa = qr[2 * t];
    qb_ = qr[2 * t + 1];
  }
  float total = 0.f;

  barrier_lds();  // init (bm) visible

  for (int step = 0; step < kN - 1; ++step) {
    // ================= phase 1: scores (all 1024 slots, static addr) =====
    uint4 ku[8];
#pragma unroll
    for (int r = 0; r < 8; ++r)
      ku[r] = ((const uint4*)(kqb + (size_t)jc[r] * kE))[t];

    // V prefetch: batches 0..3 (static addresses; hides under score dots)
    unsigned uu[4][4];
#pragma unroll
    for (int qq = 0; qq < 4; ++qq)
#pragma unroll
      for (int k = 0; k < 4; ++k) {
        int vj = w2 * 4 + 128 * qq + k;  // <= 511 here, no clamp needed
        uu[qq][k] = ((const unsigned*)(vqb + (size_t)vj * kE))[idx];
      }

    h2 q8[8];
    {
      unsigned qw[8] = {qa.x, qa.y, qa.z, qa.w, qb_.x, qb_.y, qb_.z, qb_.w};
#pragma unroll
      for (int i = 0; i < 8; ++i) q8[i] = __builtin_bit_cast(h2, qw[i]);
    }

    float den = 0.f;
#pragma unroll
    for (int r = 0; r < 8; ++r) {
      float s = dot16(ku[r], q8, 0.f);
      float hv = ((alive >> r) & 1u) ? __expf(s) : 0.f;  // dead -> exactly 0
      p[t][g + 128 * r] = hv;
      den += hv;
    }
    // den: sum across the 8 groups of this wave (preserve t = lane%8)
    den = dpp_addf<0x128>(den);  // xor8-equiv (row_ror:8)
    den += __shfl_xor(den, 16);
    den += __shfl_xor(den, 32);
    if (lane < kH) redSum[wave][lane] = den;  // lane==t for lanes 0..7
    barrier_lds();  // B1: p, redSum ready

    // ========== phase 2: ctx partials (branchless, depth-4 V pipe) =======
    // lu issued first (static addresses; consumed in phase 5 — covered by
    // this whole phase plus phases 3/4).
    uint4 lu[8];
#pragma unroll
    for (int r = 0; r < 8; ++r)
      lu[r] = ((const uint4*)(lqb + (size_t)jc[r] * kE))[t];
    {
      float a0 = 0.f, a1 = 0.f, a2 = 0.f, a3 = 0.f;
#pragma unroll
      for (int q = 0; q < 8; ++q) {
        const int s = q & 3;
        int jb = w2 * 4 + 128 * q;
        float4 pw = *(const float4*)&p[h][jb];
        {
          f2 lo = __builtin_amdgcn_cvt_pk_f32_fp8(uu[s][0], false);
          f2 hi = __builtin_amdgcn_cvt_pk_f32_fp8(uu[s][0], true);
          a0 += pw.x * lo.x; a1 += pw.x * lo.y;
          a2 += pw.x * hi.x; a3 += pw.x * hi.y;
        }
        {
          f2 lo = __builtin_amdgcn_cvt_pk_f32_fp8(uu[s][1], false);
          f2 hi = __builtin_amdgcn_cvt_pk_f32_fp8(uu[s][1], true);
          a0 += pw.y * lo.x; a1 += pw.y * lo.y;
          a2 += pw.y * hi.x; a3 += pw.y * hi.y;
        }
        {
          f2 lo = __builtin_amdgcn_cvt_pk_f32_fp8(uu[s][2], false);
          f2 hi = __builtin_amdgcn_cvt_pk_f32_fp8(uu[s][2], true);
          a0 += pw.z * lo.x; a1 += pw.z * lo.y;
          a2 += pw.z * hi.x; a3 += pw.z * hi.y;
        }
        {
          f2 lo = __builtin_amdgcn_cvt_pk_f32_fp8(uu[s][3], false);
          f2 hi = __builtin_amdgcn_cvt_pk_f32_fp8(uu[s][3], true);
          a0 += pw.w * lo.x; a1 += pw.w * lo.y;
          a2 += pw.w * hi.x; a3 += pw.w * hi.y;
        }
        if (q < 4) {  // issue batch q+4 into slot s (depth-4 pipeline)
#pragma unroll
          for (int k = 0; k < 4; ++k) {
            int vj = w2 * 4 + 128 * (q + 4) + k;
            int vjc = (vj <= 999) ? vj : 0;  // p=0 masks the dead rows
            uu[s][k] = ((const unsigned*)(vqb + (size_t)vjc * kE))[idx];
          }
        }
      }
      ((float4*)(parts + w2 * kPS))[idx] = make_float4(a0, a1, a2, a3);
    }
    barrier_lds();  // B2: parts ready

    // ====== phase 3: finalize ctx (ALL threads, DPP octet tree) ==========
    {
      int e = tid >> 3, sub = tid & 7, hh = e >> 4;
      float s = 0.f;
#pragma unroll
      for (int w4 = 0; w4 < 4; ++w4) s += parts[(sub + 8 * w4) * kPS + e];
      float d = redSum[sub][hh] + redSum[sub + 8][hh];
      s = dpp_addf<0xB1>(s);
      s = dpp_addf<0x4E>(s);
      s = dpp_addf<0x141>(s);
      d = dpp_addf<0xB1>(d);
      d = dpp_addf<0x4E>(d);
      d = dpp_addf<0x141>(d);
      if (sub == 0) ctx[e] = s / (d * kFP8Scale);
    }
    barrier_lds();  // B3: ctx ready

    // ================= phase 4: x = (bm + ctx @ Wmlp) * kQKScale =========
    {
      float xacc = 0.f;
      const float4* c4 = (const float4*)(ctx + t * 16);
#pragma unroll
      for (int k4 = 0; k4 < 4; ++k4) {
        float4 cv = c4[k4];
        xacc += cv.x * wm[4 * k4 + 0] + cv.y * wm[4 * k4 + 1] +
                cv.z * wm[4 * k4 + 2] + cv.w * wm[4 * k4 + 3];
      }
      xacc = dpp_addf<0xB1>(xacc);   // xor1
      xacc = dpp_addf<0x4E>(xacc);   // xor2
      xacc = dpp_addf<0x141>(xacc);  // xor4-equiv (octet mirror)
      if (t == 0) xh[g] = __float2half((bm[g] + xacc) * kQKScale);
    }
    barrier_lds();  // B4: xh ready

    // ================= phase 5: logits (lu already in registers) =========
    float m = -1e30f, ssum = 0.f;
    int arg = 0x7fffffff;
    {
      h2 x8[8];
      uint4 xv0 = ((const uint4*)xh)[2 * t];
      uint4 xv1 = ((const uint4*)xh)[2 * t + 1];
      unsigned xw[8] = {xv0.x, xv0.y, xv0.z, xv0.w,
                        xv1.x, xv1.y, xv1.z, xv1.w};
#pragma unroll
      for (int i = 0; i < 8; ++i) x8[i] = __builtin_bit_cast(h2, xw[i]);
#pragma unroll
      for (int r = 0; r < 8; ++r) {
        float s = dot16(lu[r], x8, 0.f);
        s = dpp_addf<0xB1>(s);
        s = dpp_addf<0x4E>(s);
        s = dpp_addf<0x141>(s);
        if (t == r && ((alive >> r) & 1u)) {  // lane t captures entry r
          m = fast_tanh(s) * 10.f;
          ssum = 1.f;
          arg = g + 128 * r;
        }
      }
    }
    // wave butterfly: DPP for 1/2/4/8, shfl for 16/32
    dpp_combine<0xB1>(m, ssum, arg);
    dpp_combine<0x4E>(m, ssum, arg);
    dpp_combine<0x141>(m, ssum, arg);
    dpp_combine<0x128>(m, ssum, arg);
#pragma unroll
    for (int off = 16; off <= 32; off <<= 1) {
      float mo = __shfl_xor(m, off);
      float so = __shfl_xor(ssum, off);
      int ao = __shfl_xor(arg, off);
      combine(m, ssum, arg, mo, so, ao);
    }
    if (lane == 0)
      redPack[wave] = make_float4(m, ssum, __int_as_float(arg), 0.f);
    barrier_lds();  // B5: per-wave reductions ready

    // ====== phase 6: all-thread final combine, q prefetch, mask update ===
    {
      float4 rp = redPack[lane & 15];
      float M = rp.x, S = rp.y;
      int Af = __float_as_int(rp.z);
      dpp_combine<0xB1>(M, S, Af);
      dpp_combine<0x4E>(M, S, Af);
      dpp_combine<0x141>(M, S, Af);
      dpp_combine<0x128>(M, S, Af);
      A = Af;
      total += -logf(S);  // chosen logit == M => log_p[act] = -log S
      // prefetch next q row (every thread knows A; load overlaps next phase)
      const uint4* qr = (const uint4*)(qsb + (size_t)A * kE);
      qa = qr[2 * t];
      qb_ = qr[2 * t + 1];
      // clear liveness bit of A (register op — no LDS, no barrier needed)
      if ((A & 127) == g) alive &= ~(1u << (A >> 7));
    }
    // no end-of-step barrier: nothing in LDS mutates between B5 and the
    // next step's B1 writes, and every wave re-reads only post-B1 data.
  }
  if (tid == 0) out[b] = total;
}

// ---------------------------------------------------------------------------
extern "C" void kernel_launch(void* const* d_in, const int* in_sizes, int n_in,
                              void* d_out, int out_size, void* d_ws,
                              size_t ws_size, hipStream_t stream) {
  const float* ne = (const float*)d_in[0];
  const float* ge = (const float*)d_in[1];
  const float* Wqkv = (const float*)d_in[2];
  const float* bqkv = (const float*)d_in[3];
  const float* Wfix = (const float*)d_in[4];
  const float* bfix = (const float*)d_in[5];
  const float* Wstep = (const float*)d_in[6];
  const float* bstep = (const float*)d_in[7];
  const float* Wmlp = (const float*)d_in[8];
  const float* bmlp = (const float*)d_in[9];
  float* out = (float*)d_out;

  size_t nkv = (size_t)kB * kN * kE;  // bytes per fp8 tensor
  unsigned char* kq = (unsigned char*)d_ws;
  unsigned char* vq = kq + nkv;
  unsigned char* lkq = vq + nkv;
  __half* qstep = (__half*)(lkq + nkv);  // 2*nkv bytes
  float* qbase = (float*)(qstep + nkv);  // 64 KB

  qkv_kernel<<<dim3(kB, (kN + 15) / 16), 384, 0, stream>>>(ne, Wqkv, bqkv, kq,
                                                           vq, lkq);
  qbase_kernel<<<kB, kE, 0, stream>>>(ne, ge, Wfix, bfix, Wstep, bstep, qbase);
  qstep_kernel<<<dim3(kB, kN / 8), 128, 0, stream>>>(ne, Wstep, qbase, qstep);
  rollout_kernel<<<kB, 1024, 0, stream>>>(Wmlp, bmlp, kq, vq, lkq, qstep, out);
}

// Round 7
// 8663.737 us; speedup vs baseline: 3.4214x; 3.4214x over previous
//
#include <hip/hip_runtime.h>
#include <hip/hip_fp16.h>

constexpr int kB = 128;
constexpr int kN = 1000;
constexpr int kE = 128;
constexpr int kH = 8;
constexpr float kFP8Scale = 64.f;         // fp8 values stored as v*64
constexpr float kQKScale = 0.25f / 64.f;  // 1/sqrt(16) folded with 1/64

typedef _Float16 h2 __attribute__((ext_vector_type(2)));
typedef float f2 __attribute__((ext_vector_type(2)));

__device__ __forceinline__ h2 pkrtz(float a, float b) {
  return __builtin_bit_cast(h2, __builtin_amdgcn_cvt_pkrtz(a, b));
}

// dot of 4 fp8 elems (packed in u, stored value*64) against 4 f16 elems.
__device__ __forceinline__ float dotq(unsigned u, h2 qa, h2 qb, float s) {
  f2 lo = __builtin_amdgcn_cvt_pk_f32_fp8(u, false);
  f2 hi = __builtin_amdgcn_cvt_pk_f32_fp8(u, true);
  h2 l16 = pkrtz(lo.x, lo.y);
  h2 h16 = pkrtz(hi.x, hi.y);
  s = __builtin_amdgcn_fdot2(l16, qa, s, false);
  s = __builtin_amdgcn_fdot2(h16, qb, s, false);
  return s;
}
// 16-elem fp8 dot (one uint4) against 16 f16 elems in q8[0..7].
__device__ __forceinline__ float dot16(uint4 tq, const h2* q8, float s) {
  s = dotq(tq.x, q8[0], q8[1], s);
  s = dotq(tq.y, q8[2], q8[3], s);
  s = dotq(tq.z, q8[4], q8[5], s);
  s = dotq(tq.w, q8[6], q8[7], s);
  return s;
}

__device__ __forceinline__ float fast_tanh(float x) {
  float t = __expf(2.f * x);
  return 1.f - 2.f / (t + 1.f);
}

__device__ __forceinline__ unsigned char enc_fp8(float v) {
  unsigned p = __builtin_amdgcn_cvt_pk_fp8_f32(v, v, 0, false);
  return (unsigned char)(p & 0xFF);
}

// online-softmax / argmax combine; tie -> smaller node id (jnp.argmax).
__device__ __forceinline__ void combine(float& m, float& s, int& a,
                                        float mo, float so, int ao) {
  bool take = (mo > m) || (mo == m && ao < a);
  float mw = take ? mo : m;
  float ml = take ? m : mo;
  float sw = take ? so : s;
  float sl = take ? s : so;
  s = sw + sl * __expf(ml - mw);
  m = mw;
  a = take ? ao : a;
}

// ---- DPP cross-lane helpers (VALU pipe, not DS) ---------------------------
// 0xB1 = quad_perm xor1, 0x4E = quad_perm xor2, 0x141 = row_half_mirror
// (xor4-equiv within octet), 0x128 = row_ror:8 (xor8-equiv within 16 lanes).
template <int CTRL>
__device__ __forceinline__ float dpp_bcastf(float x) {
  return __builtin_bit_cast(
      float, __builtin_amdgcn_update_dpp(0, __builtin_bit_cast(int, x), CTRL,
                                         0xf, 0xf, true));
}
template <int CTRL>
__device__ __forceinline__ int dpp_bcasti(int x) {
  return __builtin_amdgcn_update_dpp(0, x, CTRL, 0xf, 0xf, true);
}
template <int CTRL>
__device__ __forceinline__ float dpp_addf(float x) {
  return x + dpp_bcastf<CTRL>(x);
}
template <int CTRL>
__device__ __forceinline__ void dpp_combine(float& m, float& s, int& a) {
  float mo = dpp_bcastf<CTRL>(m);
  float so = dpp_bcastf<CTRL>(s);
  int ao = dpp_bcasti<CTRL>(a);
  combine(m, s, a, mo, so, ao);
}

// LDS-only barrier: drains DS ops, leaves global register-loads in flight.
__device__ __forceinline__ void barrier_lds() {
  asm volatile("s_waitcnt lgkmcnt(0)" ::: "memory");
  __builtin_amdgcn_s_barrier();
  asm volatile("" ::: "memory");
}

// ---------------------------------------------------------------------------
// Kernel A: qkv projection -> fp8 (value*64) k / v / logit_k.
// ---------------------------------------------------------------------------
__global__ __launch_bounds__(384) void qkv_kernel(
    const float* __restrict__ ne, const float* __restrict__ Wqkv,
    const float* __restrict__ bqkv, unsigned char* __restrict__ kq,
    unsigned char* __restrict__ vq, unsigned char* __restrict__ lkq) {
  __shared__ float rows[16 * kE];
  int b = blockIdx.x;
  int n0 = blockIdx.y * 16;
  int ntile = min(16, kN - n0);
  int tid = threadIdx.x;

  for (int idx = tid; idx < ntile * kE; idx += 384)
    rows[idx] = ne[(b * kN + n0) * kE + idx];
  __syncthreads();

  int j = tid;  // 0..383
  float acc[16];
#pragma unroll
  for (int r = 0; r < 16; ++r) acc[r] = 0.f;
  for (int i = 0; i < kE; ++i) {
    float w = Wqkv[i * (3 * kE) + j];
#pragma unroll
    for (int r = 0; r < 16; ++r) acc[r] += rows[r * kE + i] * w;
  }
  float bias = bqkv[j];
  unsigned char* dst;
  int col;
  if (j < kE) { dst = kq; col = j; }
  else if (j < 2 * kE) { dst = vq; col = j - kE; }
  else { dst = lkq; col = j - 2 * kE; }
  for (int r = 0; r < ntile; ++r)
    dst[(size_t)(b * kN + n0 + r) * kE + col] =
        enc_fp8((acc[r] + bias) * kFP8Scale);
}

// ---------------------------------------------------------------------------
// Kernel B: qbase[b] = ge@Wfix + bfix + first@Wstep_top + bstep  (fp32)
// ---------------------------------------------------------------------------
__global__ __launch_bounds__(128) void qbase_kernel(
    const float* __restrict__ ne, const float* __restrict__ ge,
    const float* __restrict__ Wfix, const float* __restrict__ bfix,
    const float* __restrict__ Wstep, const float* __restrict__ bstep,
    float* __restrict__ qbase) {
  __shared__ float g[kE], f[kE];
  int b = blockIdx.x, e = threadIdx.x;
  g[e] = ge[b * kE + e];
  f[e] = ne[(size_t)b * kN * kE + e];  // node 0
  __syncthreads();
  float acc = bfix[e] + bstep[e];
  for (int i = 0; i < kE; ++i)
    acc += g[i] * Wfix[i * kE + e] + f[i] * Wstep[i * kE + e];
  qbase[b * kE + e] = acc;
}

// ---------------------------------------------------------------------------
// Kernel B2: qstep[b,n] = (qbase[b] + ne[b,n] @ Wbot) * kQKScale, f16.
// ---------------------------------------------------------------------------
__global__ __launch_bounds__(128) void qstep_kernel(
    const float* __restrict__ ne, const float* __restrict__ Wstep,
    const float* __restrict__ qbase, __half* __restrict__ qstep) {
  __shared__ float rows[8 * kE];
  int b = blockIdx.x;
  int n0 = blockIdx.y * 8;
  int tid = threadIdx.x;
  const float* Wbot = Wstep + kE * kE;

  for (int idx = tid; idx < 8 * kE; idx += 128)
    rows[idx] = ne[((size_t)b * kN + n0) * kE + idx];
  __syncthreads();

  float acc[8];
#pragma unroll
  for (int r = 0; r < 8; ++r) acc[r] = 0.f;
  for (int i = 0; i < kE; ++i) {
    float w = Wbot[i * kE + tid];
#pragma unroll
    for (int r = 0; r < 8; ++r) acc[r] += rows[r * kE + i] * w;
  }
  float qb = qbase[b * kE + tid];
#pragma unroll
  for (int r = 0; r < 8; ++r)
    qstep[((size_t)b * kN + n0 + r) * kE + tid] =
        __float2half((qb + acc[r]) * kQKScale);
}

// ---------------------------------------------------------------------------
// Kernel C: 999-step rollout, one 1024-thread block per batch element.
// FUSED scores+ctx structure (head-alignment trick):
//  * thread (g,t)'s K chunk t IS head t's full 16 dims, so hv=exp(dot16) is
//    the complete attention weight p[t][j]; the ctx elements it weights are
//    V[j][16t..16t+16) — the SAME uint4 index t of the same row.  The whole
//    p·V accumulation stays in registers: no p[] LDS array, no barrier
//    between score and V phases, V gathers share the K address pattern.
//  * per-slot compute doubles (K-dot + V-acc) -> depth-2 slot pipeline
//    covers ~2x more gather latency.
//  * ctx reduction: DPP gw-pair fold -> parts[e][64 chunks] with a
//    bank-injective column swizzle ((c+4t)&63): 32 writer lanes hit 32
//    distinct banks (20t+cp mod 32 injective).
//  * Wmlp staged in LDS f32 (one block/CU; frees 16 VGPRs for K/V bufs).
//  * sorted rem + local shift-remove (round-5, proven).  5 barriers/step.
// ---------------------------------------------------------------------------
__global__ __launch_bounds__(1024) void rollout_kernel(
    const float* __restrict__ Wmlp, const float* __restrict__ bmlp,
    const unsigned char* __restrict__ kq, const unsigned char* __restrict__ vq,
    const unsigned char* __restrict__ lkq, const __half* __restrict__ qstep,
    float* __restrict__ out) {
  __shared__ __align__(16) int rem[1024];       // SORTED live ids (padded)
  __shared__ __align__(16) float parts[kE][65]; // ctx chunk partials, 33 KB
  __shared__ __align__(16) float wmT[kE][132];  // wmT[g][i]=Wmlp[i][g], 68 KB
  __shared__ float bm[kE];
  __shared__ __align__(16) float ctx[kE];
  __shared__ __align__(16) __half xh[kE];
  __shared__ float redSum[16][kH];
  __shared__ __align__(16) float4 redPack[16];  // (m, ssum, argbits, -)

  int b = blockIdx.x;
  int tid = threadIdx.x;
  int lane = tid & 63;
  int wave = tid >> 6;
  int g = tid >> 3;  // node-group 0..127; slots j = g + 128r
  int t = tid & 7;   // head / uint4 chunk within row

  const unsigned char* kqb = kq + (size_t)b * kN * kE;
  const unsigned char* vqb = vq + (size_t)b * kN * kE;
  const unsigned char* lqb = lkq + (size_t)b * kN * kE;
  const __half* qsb = qstep + (size_t)b * kN * kE;

  // stage Wmlp transposed into LDS (one-time; coalesced reads)
#pragma unroll
  for (int m = 0; m < 16; ++m) {
    int idx = tid * 16 + m;  // 0..16383
    wmT[idx & 127][idx >> 7] = Wmlp[idx];
  }
  // init sorted live list (padded with valid ids for safe speculative reads)
  rem[tid] = (tid < kN - 1) ? tid + 1 : kN - 1;
  if (tid < kE) bm[tid] = bmlp[tid];

  // current action + its q row (prefetched into registers; node 0 first)
  int A = 0;
  uint4 qa, qb_;
  {
    const uint4* qr = (const uint4*)qsb;
    qa = qr[2 * t];
    qb_ = qr[2 * t + 1];
  }
  float total = 0.f;

  barrier_lds();  // init visible

  for (int step = 0; step < kN - 1; ++step) {
    int R = kN - 1 - step;  // live count (deterministic)

    // ========== phase A: fused scores + ctx accumulation =================
    int jn[8];
#pragma unroll
    for (int r = 0; r < 8; ++r) {
      int j = g + 128 * r;
      jn[r] = (j < R) ? rem[j] : -1;
    }
    h2 q8[8];
    {
      unsigned qw[8] = {qa.x, qa.y, qa.z, qa.w, qb_.x, qb_.y, qb_.z, qb_.w};
#pragma unroll
      for (int i = 0; i < 8; ++i) q8[i] = __builtin_bit_cast(h2, qw[i]);
    }
    uint4 kb0, vb0, kb1, vb1;
    if (jn[0] >= 0) {
      kb0 = ((const uint4*)(kqb + (size_t)jn[0] * kE))[t];
      vb0 = ((const uint4*)(vqb + (size_t)jn[0] * kE))[t];
    }
    if (jn[1] >= 0) {
      kb1 = ((const uint4*)(kqb + (size_t)jn[1] * kE))[t];
      vb1 = ((const uint4*)(vqb + (size_t)jn[1] * kE))[t];
    }
    float acc[16];
#pragma unroll
    for (int i = 0; i < 16; ++i) acc[i] = 0.f;
    float den = 0.f;
#pragma unroll
    for (int r = 0; r < 8; ++r) {
      if (jn[r] < 0) break;  // sorted rem: deadness is monotone in r
      uint4 kk = (r & 1) ? kb1 : kb0;
      uint4 vv = (r & 1) ? vb1 : vb0;
      if (r + 2 < 8 && jn[r + 2] >= 0) {  // depth-2 slot pipeline
        if (r & 1) {
          kb1 = ((const uint4*)(kqb + (size_t)jn[r + 2] * kE))[t];
          vb1 = ((const uint4*)(vqb + (size_t)jn[r + 2] * kE))[t];
        } else {
          kb0 = ((const uint4*)(kqb + (size_t)jn[r + 2] * kE))[t];
          vb0 = ((const uint4*)(vqb + (size_t)jn[r + 2] * kE))[t];
        }
      }
      float s = dot16(kk, q8, 0.f);
      float hv = __expf(s);  // full head-t score (d=16): scores tiny
      den += hv;
      unsigned uu[4] = {vv.x, vv.y, vv.z, vv.w};
#pragma unroll
      for (int c = 0; c < 4; ++c) {
        f2 lo = __builtin_amdgcn_cvt_pk_f32_fp8(uu[c], false);
        f2 hi = __builtin_amdgcn_cvt_pk_f32_fp8(uu[c], true);
        acc[4 * c + 0] += hv * lo.x;
        acc[4 * c + 1] += hv * lo.y;
        acc[4 * c + 2] += hv * hi.x;
        acc[4 * c + 3] += hv * hi.y;
      }
    }
    // den: reduce over the 8 g-groups of this wave (preserve t = lane%8)
    den = dpp_addf<0x128>(den);
    den += __shfl_xor(den, 16);
    den += __shfl_xor(den, 32);
    if (lane < kH) redSum[wave][lane] = den;  // lane==t for lanes 0..7
    // acc: gw-pair fold (VALU), then even-gw lanes write 64-chunk parts
#pragma unroll
    for (int i = 0; i < 16; ++i) acc[i] = dpp_addf<0x128>(acc[i]);
    if (((lane >> 3) & 1) == 0) {
      int chunk = wave * 4 + (lane >> 4);  // 0..63
#pragma unroll
      for (int i = 0; i < 16; ++i)
        parts[t * 16 + i][(chunk + 4 * t) & 63] = acc[i];  // bank-injective
    }
    // lu prefetch (held in regs through phases C/D; consumed in E)
    uint4 lu[8];
#pragma unroll
    for (int r = 0; r < 8; ++r)
      if (jn[r] >= 0) lu[r] = ((const uint4*)(lqb + (size_t)jn[r] * kE))[t];
    barrier_lds();  // B1: parts, redSum ready

    // ========== phase C: finalize ctx (all threads, DPP octet tree) ======
    {
      int e = tid >> 3, k = tid & 7, hh = e >> 4;
      float s = 0.f;
#pragma unroll
      for (int m = 0; m < 8; ++m)
        s += parts[e][((8 * k + m) + 4 * hh) & 63];
      float d = redSum[2 * k][hh] + redSum[2 * k + 1][hh];
      s = dpp_addf<0xB1>(s);
      s = dpp_addf<0x4E>(s);
      s = dpp_addf<0x141>(s);
      d = dpp_addf<0xB1>(d);
      d = dpp_addf<0x4E>(d);
      d = dpp_addf<0x141>(d);
      if (k == 0) ctx[e] = s / (d * kFP8Scale);
    }
    barrier_lds();  // B2: ctx ready

    // ========== phase D: x = (bm + ctx @ Wmlp) * kQKScale (wm from LDS) ==
    {
      float xacc = 0.f;
      const float4* c4 = (const float4*)(ctx + t * 16);
      const float4* w4 = (const float4*)(&wmT[g][t * 16]);
#pragma unroll
      for (int k4 = 0; k4 < 4; ++k4) {
        float4 cv = c4[k4];
        float4 wv = w4[k4];
        xacc += cv.x * wv.x + cv.y * wv.y + cv.z * wv.z + cv.w * wv.w;
      }
      xacc = dpp_addf<0xB1>(xacc);
      xacc = dpp_addf<0x4E>(xacc);
      xacc = dpp_addf<0x141>(xacc);
      if (t == 0) xh[g] = __float2half((bm[g] + xacc) * kQKScale);
    }
    barrier_lds();  // B3: xh ready

    // ========== phase E: logits (lu already in registers) ================
    // rem[tid]/rem[tid+1] read NOW; B4 fences them from the phase-F write.
    int myv = rem[tid];
    int nxt = rem[(tid < 1023) ? tid + 1 : 1023];
    float m = -1e30f, ssum = 0.f;
    int arg = 0x7fffffff;
    {
      h2 x8[8];
      uint4 xv0 = ((const uint4*)xh)[2 * t];
      uint4 xv1 = ((const uint4*)xh)[2 * t + 1];
      unsigned xw[8] = {xv0.x, xv0.y, xv0.z, xv0.w,
                        xv1.x, xv1.y, xv1.z, xv1.w};
#pragma unroll
      for (int i = 0; i < 8; ++i) x8[i] = __builtin_bit_cast(h2, xw[i]);
#pragma unroll
      for (int r = 0; r < 8; ++r)
        if (jn[r] >= 0) {  // uniform within each octet (depends on g only)
          float s = dot16(lu[r], x8, 0.f);
          s = dpp_addf<0xB1>(s);
          s = dpp_addf<0x4E>(s);
          s = dpp_addf<0x141>(s);
          if (t == r) {  // lane t captures entry r
            m = fast_tanh(s) * 10.f;
            ssum = 1.f;
            arg = jn[r];
          }
        }
    }
    // wave butterfly: DPP for 1/2/4/8, shfl for 16/32
    dpp_combine<0xB1>(m, ssum, arg);
    dpp_combine<0x4E>(m, ssum, arg);
    dpp_combine<0x141>(m, ssum, arg);
    dpp_combine<0x128>(m, ssum, arg);
#pragma unroll
    for (int off = 16; off <= 32; off <<= 1) {
      float mo = __shfl_xor(m, off);
      float so = __shfl_xor(ssum, off);
      int ao = __shfl_xor(arg, off);
      combine(m, ssum, arg, mo, so, ao);
    }
    if (lane == 0)
      redPack[wave] = make_float4(m, ssum, __int_as_float(arg), 0.f);
    barrier_lds();  // B4: reductions ready; rem reads fenced from writes

    // ====== phase F: final combine (all threads), q prefetch, shift ======
    {
      float4 rp = redPack[lane & 15];
      float M = rp.x, S = rp.y;
      int Af = __float_as_int(rp.z);
      dpp_combine<0xB1>(M, S, Af);
      dpp_combine<0x4E>(M, S, Af);
      dpp_combine<0x141>(M, S, Af);
      dpp_combine<0x128>(M, S, Af);
      A = Af;
      total += -logf(S);  // chosen logit == M => log_p[act] = -log S
      // prefetch next q row (every thread knows A; load crosses B5)
      const uint4* qr = (const uint4*)(qsb + (size_t)A * kE);
      qa = qr[2 * t];
      qb_ = qr[2 * t + 1];
      // sorted shift-remove: shift condition is local (id >= A)
      if (tid < R - 1 && myv >= A) rem[tid] = nxt;
    }
    barrier_lds();  // B5: rem updated for next step
  }
  if (tid == 0) out[b] = total;
}

// ---------------------------------------------------------------------------
extern "C" void kernel_launch(void* const* d_in, const int* in_sizes, int n_in,
                              void* d_out, int out_size, void* d_ws,
                              size_t ws_size, hipStream_t stream) {
  const float* ne = (const float*)d_in[0];
  const float* ge = (const float*)d_in[1];
  const float* Wqkv = (const float*)d_in[2];
  const float* bqkv = (const float*)d_in[3];
  const float* Wfix = (const float*)d_in[4];
  const float* bfix = (const float*)d_in[5];
  const float* Wstep = (const float*)d_in[6];
  const float* bstep = (const float*)d_in[7];
  const float* Wmlp = (const float*)d_in[8];
  const float* bmlp = (const float*)d_in[9];
  float* out = (float*)d_out;

  size_t nkv = (size_t)kB * kN * kE;  // bytes per fp8 tensor
  unsigned char* kq = (unsigned char*)d_ws;
  unsigned char* vq = kq + nkv;
  unsigned char* lkq = vq + nkv;
  __half* qstep = (__half*)(lkq + nkv);  // 2*nkv bytes
  float* qbase = (float*)(qstep + nkv);  // 64 KB

  qkv_kernel<<<dim3(kB, (kN + 15) / 16), 384, 0, stream>>>(ne, Wqkv, bqkv, kq,
                                                           vq, lkq);
  qbase_kernel<<<kB, kE, 0, stream>>>(ne, ge, Wfix, bfix, Wstep, bstep, qbase);
  qstep_kernel<<<dim3(kB, kN / 8), 128, 0, stream>>>(ne, Wstep, qbase, qstep);
  rollout_kernel<<<kB, 1024, 0, stream>>>(Wmlp, bmlp, kq, vq, lkq, qstep, out);
}

// Round 8
// 8657.474 us; speedup vs baseline: 3.4239x; 1.0007x over previous
//
#include <hip/hip_runtime.h>
#include <hip/hip_fp16.h>

constexpr int kB = 128;
constexpr int kN = 1000;
constexpr int kE = 128;
constexpr int kH = 8;
constexpr float kFP8Scale = 64.f;         // fp8 values stored as v*64
constexpr float kQKScale = 0.25f / 64.f;  // 1/sqrt(16) folded with 1/64

typedef _Float16 h2 __attribute__((ext_vector_type(2)));
typedef float f2 __attribute__((ext_vector_type(2)));

__device__ __forceinline__ h2 pkrtz(float a, float b) {
  return __builtin_bit_cast(h2, __builtin_amdgcn_cvt_pkrtz(a, b));
}

// dot of 4 fp8 elems (packed in u, stored value*64) against 4 f16 elems.
__device__ __forceinline__ float dotq(unsigned u, h2 qa, h2 qb, float s) {
  f2 lo = __builtin_amdgcn_cvt_pk_f32_fp8(u, false);
  f2 hi = __builtin_amdgcn_cvt_pk_f32_fp8(u, true);
  h2 l16 = pkrtz(lo.x, lo.y);
  h2 h16 = pkrtz(hi.x, hi.y);
  s = __builtin_amdgcn_fdot2(l16, qa, s, false);
  s = __builtin_amdgcn_fdot2(h16, qb, s, false);
  return s;
}
// 16-elem fp8 dot (one uint4) against 16 f16 elems in q8[0..7].
__device__ __forceinline__ float dot16(uint4 tq, const h2* q8, float s) {
  s = dotq(tq.x, q8[0], q8[1], s);
  s = dotq(tq.y, q8[2], q8[3], s);
  s = dotq(tq.z, q8[4], q8[5], s);
  s = dotq(tq.w, q8[6], q8[7], s);
  return s;
}

__device__ __forceinline__ float fast_tanh(float x) {
  float t = __expf(2.f * x);
  return 1.f - 2.f / (t + 1.f);
}

__device__ __forceinline__ unsigned char enc_fp8(float v) {
  unsigned p = __builtin_amdgcn_cvt_pk_fp8_f32(v, v, 0, false);
  return (unsigned char)(p & 0xFF);
}

// online-softmax / argmax combine; tie -> smaller node id (jnp.argmax).
__device__ __forceinline__ void combine(float& m, float& s, int& a,
                                        float mo, float so, int ao) {
  bool take = (mo > m) || (mo == m && ao < a);
  float mw = take ? mo : m;
  float ml = take ? m : mo;
  float sw = take ? so : s;
  float sl = take ? s : so;
  s = sw + sl * __expf(ml - mw);
  m = mw;
  a = take ? ao : a;
}

// ---- DPP cross-lane helpers (VALU pipe, not DS) ---------------------------
// 0xB1 = quad_perm xor1, 0x4E = quad_perm xor2, 0x141 = row_half_mirror
// (xor4-equiv within octet), 0x128 = row_ror:8 (xor8-equiv within 16 lanes).
template <int CTRL>
__device__ __forceinline__ float dpp_bcastf(float x) {
  return __builtin_bit_cast(
      float, __builtin_amdgcn_update_dpp(0, __builtin_bit_cast(int, x), CTRL,
                                         0xf, 0xf, true));
}
template <int CTRL>
__device__ __forceinline__ int dpp_bcasti(int x) {
  return __builtin_amdgcn_update_dpp(0, x, CTRL, 0xf, 0xf, true);
}
template <int CTRL>
__device__ __forceinline__ float dpp_addf(float x) {
  return x + dpp_bcastf<CTRL>(x);
}
template <int CTRL>
__device__ __forceinline__ void dpp_combine(float& m, float& s, int& a) {
  float mo = dpp_bcastf<CTRL>(m);
  float so = dpp_bcastf<CTRL>(s);
  int ao = dpp_bcasti<CTRL>(a);
  combine(m, s, a, mo, so, ao);
}

// LDS-only barrier: drains DS ops, leaves global register-loads in flight.
__device__ __forceinline__ void barrier_lds() {
  asm volatile("s_waitcnt lgkmcnt(0)" ::: "memory");
  __builtin_amdgcn_s_barrier();
  asm volatile("" ::: "memory");
}

// ---------------------------------------------------------------------------
// Kernel A: qkv projection -> fp8 (value*64) k / v / logit_k.
// ---------------------------------------------------------------------------
__global__ __launch_bounds__(384) void qkv_kernel(
    const float* __restrict__ ne, const float* __restrict__ Wqkv,
    const float* __restrict__ bqkv, unsigned char* __restrict__ kq,
    unsigned char* __restrict__ vq, unsigned char* __restrict__ lkq) {
  __shared__ float rows[16 * kE];
  int b = blockIdx.x;
  int n0 = blockIdx.y * 16;
  int ntile = min(16, kN - n0);
  int tid = threadIdx.x;

  for (int idx = tid; idx < ntile * kE; idx += 384)
    rows[idx] = ne[(b * kN + n0) * kE + idx];
  __syncthreads();

  int j = tid;  // 0..383
  float acc[16];
#pragma unroll
  for (int r = 0; r < 16; ++r) acc[r] = 0.f;
  for (int i = 0; i < kE; ++i) {
    float w = Wqkv[i * (3 * kE) + j];
#pragma unroll
    for (int r = 0; r < 16; ++r) acc[r] += rows[r * kE + i] * w;
  }
  float bias = bqkv[j];
  unsigned char* dst;
  int col;
  if (j < kE) { dst = kq; col = j; }
  else if (j < 2 * kE) { dst = vq; col = j - kE; }
  else { dst = lkq; col = j - 2 * kE; }
  for (int r = 0; r < ntile; ++r)
    dst[(size_t)(b * kN + n0 + r) * kE + col] =
        enc_fp8((acc[r] + bias) * kFP8Scale);
}

// ---------------------------------------------------------------------------
// Kernel B: qbase[b] = ge@Wfix + bfix + first@Wstep_top + bstep  (fp32)
// ---------------------------------------------------------------------------
__global__ __launch_bounds__(128) void qbase_kernel(
    const float* __restrict__ ne, const float* __restrict__ ge,
    const float* __restrict__ Wfix, const float* __restrict__ bfix,
    const float* __restrict__ Wstep, const float* __restrict__ bstep,
    float* __restrict__ qbase) {
  __shared__ float g[kE], f[kE];
  int b = blockIdx.x, e = threadIdx.x;
  g[e] = ge[b * kE + e];
  f[e] = ne[(size_t)b * kN * kE + e];  // node 0
  __syncthreads();
  float acc = bfix[e] + bstep[e];
  for (int i = 0; i < kE; ++i)
    acc += g[i] * Wfix[i * kE + e] + f[i] * Wstep[i * kE + e];
  qbase[b * kE + e] = acc;
}

// ---------------------------------------------------------------------------
// Kernel B2: qstep[b,n] = (qbase[b] + ne[b,n] @ Wbot) * kQKScale, f16.
// ---------------------------------------------------------------------------
__global__ __launch_bounds__(128) void qstep_kernel(
    const float* __restrict__ ne, const float* __restrict__ Wstep,
    const float* __restrict__ qbase, __half* __restrict__ qstep) {
  __shared__ float rows[8 * kE];
  int b = blockIdx.x;
  int n0 = blockIdx.y * 8;
  int tid = threadIdx.x;
  const float* Wbot = Wstep + kE * kE;

  for (int idx = tid; idx < 8 * kE; idx += 128)
    rows[idx] = ne[((size_t)b * kN + n0) * kE + idx];
  __syncthreads();

  float acc[8];
#pragma unroll
  for (int r = 0; r < 8; ++r) acc[r] = 0.f;
  for (int i = 0; i < kE; ++i) {
    float w = Wbot[i * kE + tid];
#pragma unroll
    for (int r = 0; r < 8; ++r) acc[r] += rows[r * kE + i] * w;
  }
  float qb = qbase[b * kE + tid];
#pragma unroll
  for (int r = 0; r < 8; ++r)
    qstep[((size_t)b * kN + n0 + r) * kE + tid] =
        __float2half((qb + acc[r]) * kQKScale);
}

// ---------------------------------------------------------------------------
// Kernel C: 999-step rollout, one 1024-thread block per batch element.
// Round-7 fused structure + cross-step slot-0/1 prefetch:
//  * head-alignment fusion: thread (g,t)'s hv=exp(dot16(K chunk t)) is the
//    full head-t weight; p·V accumulates in registers (no p[] LDS).
//  * NEW: slots 0/1 K+V for step s+1 issued in step s's phase F using the
//    LOCALLY PATCHED sorted rem (next[j] = old[j]<A ? old[j] : old[j+1];
//    old values read race-free in phase E, pre-B4).  Loads cross the
//    LDS-only B5 in flight and land during q8 unpack / jn reads -> the
//    ~400-900cy top-of-step gather bubble disappears.  Cross-barrier live
//    set ~34 VGPR (q 8 + kb/vb 16 + jn 2) — fits the 64-VGPR wall.
//  * wmT stride 132 -> 140: phase-D ds_read_b128 bank base (12g+16t)%32
//    gives 8 distinct quads, residual 2-way (free) vs prior 4-way.
//  * sorted rem + local shift-remove.  5 barriers/step.
// ---------------------------------------------------------------------------
__global__ __launch_bounds__(1024) void rollout_kernel(
    const float* __restrict__ Wmlp, const float* __restrict__ bmlp,
    const unsigned char* __restrict__ kq, const unsigned char* __restrict__ vq,
    const unsigned char* __restrict__ lkq, const __half* __restrict__ qstep,
    float* __restrict__ out) {
  __shared__ __align__(16) int rem[1024];       // SORTED live ids (padded)
  __shared__ __align__(16) float parts[kE][65]; // ctx chunk partials, 33 KB
  __shared__ __align__(16) float wmT[kE][140];  // wmT[g][i]=Wmlp[i][g], 70 KB
  __shared__ float bm[kE];
  __shared__ __align__(16) float ctx[kE];
  __shared__ __align__(16) __half xh[kE];
  __shared__ float redSum[16][kH];
  __shared__ __align__(16) float4 redPack[16];  // (m, ssum, argbits, -)

  int b = blockIdx.x;
  int tid = threadIdx.x;
  int lane = tid & 63;
  int wave = tid >> 6;
  int g = tid >> 3;  // node-group 0..127; slots j = g + 128r
  int t = tid & 7;   // head / uint4 chunk within row

  const unsigned char* kqb = kq + (size_t)b * kN * kE;
  const unsigned char* vqb = vq + (size_t)b * kN * kE;
  const unsigned char* lqb = lkq + (size_t)b * kN * kE;
  const __half* qsb = qstep + (size_t)b * kN * kE;

  // stage Wmlp transposed into LDS (one-time; coalesced reads)
#pragma unroll
  for (int m = 0; m < 16; ++m) {
    int idx = tid * 16 + m;  // 0..16383
    wmT[idx & 127][idx >> 7] = Wmlp[idx];
  }
  // init sorted live list (padded with valid ids for safe speculative reads)
  rem[tid] = (tid < kN - 1) ? tid + 1 : kN - 1;
  if (tid < kE) bm[tid] = bmlp[tid];

  // current action + its q row (prefetched into registers; node 0 first)
  int A = 0;
  uint4 qa, qb_;
  {
    const uint4* qr = (const uint4*)qsb;
    qa = qr[2 * t];
    qb_ = qr[2 * t + 1];
  }
  float total = 0.f;

  barrier_lds();  // init visible

  // step-0 slot-0/1 prefetch (initial rem[j] = j+1)
  int pjn0 = (g < kN - 1) ? g + 1 : -1;
  int pjn1 = (g + 128 < kN - 1) ? g + 129 : -1;
  uint4 kb0, vb0, kb1, vb1;
  if (pjn0 >= 0) {
    kb0 = ((const uint4*)(kqb + (size_t)pjn0 * kE))[t];
    vb0 = ((const uint4*)(vqb + (size_t)pjn0 * kE))[t];
  }
  if (pjn1 >= 0) {
    kb1 = ((const uint4*)(kqb + (size_t)pjn1 * kE))[t];
    vb1 = ((const uint4*)(vqb + (size_t)pjn1 * kE))[t];
  }

  for (int step = 0; step < kN - 1; ++step) {
    int R = kN - 1 - step;  // live count (deterministic)

    // ========== phase A: fused scores + ctx accumulation =================
    int jn[8];
    jn[0] = pjn0;  // prefetched last step (patched rem — proven equal)
    jn[1] = pjn1;
#pragma unroll
    for (int r = 2; r < 8; ++r) {
      int j = g + 128 * r;
      jn[r] = (j < R) ? rem[j] : -1;
    }
    h2 q8[8];
    {
      unsigned qw[8] = {qa.x, qa.y, qa.z, qa.w, qb_.x, qb_.y, qb_.z, qb_.w};
#pragma unroll
      for (int i = 0; i < 8; ++i) q8[i] = __builtin_bit_cast(h2, qw[i]);
    }
    float acc[16];
#pragma unroll
    for (int i = 0; i < 16; ++i) acc[i] = 0.f;
    float den = 0.f;
#pragma unroll
    for (int r = 0; r < 8; ++r) {
      if (jn[r] < 0) break;  // sorted rem: deadness is monotone in r
      uint4 kk = (r & 1) ? kb1 : kb0;
      uint4 vv = (r & 1) ? vb1 : vb0;
      if (r + 2 < 8 && jn[r + 2] >= 0) {  // depth-2 slot pipeline
        if (r & 1) {
          kb1 = ((const uint4*)(kqb + (size_t)jn[r + 2] * kE))[t];
          vb1 = ((const uint4*)(vqb + (size_t)jn[r + 2] * kE))[t];
        } else {
          kb0 = ((const uint4*)(kqb + (size_t)jn[r + 2] * kE))[t];
          vb0 = ((const uint4*)(vqb + (size_t)jn[r + 2] * kE))[t];
        }
      }
      float s = dot16(kk, q8, 0.f);
      float hv = __expf(s);  // full head-t score (d=16): scores tiny
      den += hv;
      unsigned uu[4] = {vv.x, vv.y, vv.z, vv.w};
#pragma unroll
      for (int c = 0; c < 4; ++c) {
        f2 lo = __builtin_amdgcn_cvt_pk_f32_fp8(uu[c], false);
        f2 hi = __builtin_amdgcn_cvt_pk_f32_fp8(uu[c], true);
        acc[4 * c + 0] += hv * lo.x;
        acc[4 * c + 1] += hv * lo.y;
        acc[4 * c + 2] += hv * hi.x;
        acc[4 * c + 3] += hv * hi.y;
      }
    }
    // lu prefetch first (long cover: rest of A + B1 + C + D)
    uint4 lu[8];
#pragma unroll
    for (int r = 0; r < 8; ++r)
      if (jn[r] >= 0) lu[r] = ((const uint4*)(lqb + (size_t)jn[r] * kE))[t];
    // den: reduce over the 8 g-groups of this wave (preserve t = lane%8)
    den = dpp_addf<0x128>(den);
    den += __shfl_xor(den, 16);
    den += __shfl_xor(den, 32);
    if (lane < kH) redSum[wave][lane] = den;  // lane==t for lanes 0..7
    // acc: gw-pair fold (VALU), then even-gw lanes write 64-chunk parts
#pragma unroll
    for (int i = 0; i < 16; ++i) acc[i] = dpp_addf<0x128>(acc[i]);
    if (((lane >> 3) & 1) == 0) {
      int chunk = wave * 4 + (lane >> 4);  // 0..63
#pragma unroll
      for (int i = 0; i < 16; ++i)
        parts[t * 16 + i][(chunk + 4 * t) & 63] = acc[i];  // bank-injective
    }
    barrier_lds();  // B1: parts, redSum ready

    // ========== phase C: finalize ctx (all threads, DPP octet tree) ======
    {
      int e = tid >> 3, k = tid & 7, hh = e >> 4;
      float s = 0.f;
#pragma unroll
      for (int m = 0; m < 8; ++m)
        s += parts[e][((8 * k + m) + 4 * hh) & 63];
      float d = redSum[2 * k][hh] + redSum[2 * k + 1][hh];
      s = dpp_addf<0xB1>(s);
      s = dpp_addf<0x4E>(s);
      s = dpp_addf<0x141>(s);
      d = dpp_addf<0xB1>(d);
      d = dpp_addf<0x4E>(d);
      d = dpp_addf<0x141>(d);
      if (k == 0) ctx[e] = s / (d * kFP8Scale);
    }
    barrier_lds();  // B2: ctx ready

    // ========== phase D: x = (bm + ctx @ Wmlp) * kQKScale (wm from LDS) ==
    {
      float xacc = 0.f;
      const float4* c4 = (const float4*)(ctx + t * 16);
      const float4* w4 = (const float4*)(&wmT[g][t * 16]);
#pragma unroll
      for (int k4 = 0; k4 < 4; ++k4) {
        float4 cv = c4[k4];
        float4 wv = w4[k4];
        xacc += cv.x * wv.x + cv.y * wv.y + cv.z * wv.z + cv.w * wv.w;
      }
      xacc = dpp_addf<0xB1>(xacc);
      xacc = dpp_addf<0x4E>(xacc);
      xacc = dpp_addf<0x141>(xacc);
      if (t == 0) xh[g] = __float2half((bm[g] + xacc) * kQKScale);
    }
    barrier_lds();  // B3: xh ready

    // ========== phase E: logits (lu already in registers) ================
    // Read rem values needed for (a) shift-remove and (b) next-step slot-0/1
    // prefetch NOW (pre-B4): B4 fences these reads from phase-F writes.
    int myv = rem[tid];
    int nxt = rem[(tid < 1023) ? tid + 1 : 1023];
    int pr0 = rem[g];
    int pr1 = rem[g + 1];
    int pr2 = rem[g + 128];
    int pr3 = rem[g + 129];
    float m = -1e30f, ssum = 0.f;
    int arg = 0x7fffffff;
    {
      h2 x8[8];
      uint4 xv0 = ((const uint4*)xh)[2 * t];
      uint4 xv1 = ((const uint4*)xh)[2 * t + 1];
      unsigned xw[8] = {xv0.x, xv0.y, xv0.z, xv0.w,
                        xv1.x, xv1.y, xv1.z, xv1.w};
#pragma unroll
      for (int i = 0; i < 8; ++i) x8[i] = __builtin_bit_cast(h2, xw[i]);
#pragma unroll
      for (int r = 0; r < 8; ++r)
        if (jn[r] >= 0) {  // uniform within each octet (depends on g only)
          float s = dot16(lu[r], x8, 0.f);
          s = dpp_addf<0xB1>(s);
          s = dpp_addf<0x4E>(s);
          s = dpp_addf<0x141>(s);
          if (t == r) {  // lane t captures entry r
            m = fast_tanh(s) * 10.f;
            ssum = 1.f;
            arg = jn[r];
          }
        }
    }
    // wave butterfly: DPP for 1/2/4/8, shfl for 16/32
    dpp_combine<0xB1>(m, ssum, arg);
    dpp_combine<0x4E>(m, ssum, arg);
    dpp_combine<0x141>(m, ssum, arg);
    dpp_combine<0x128>(m, ssum, arg);
#pragma unroll
    for (int off = 16; off <= 32; off <<= 1) {
      float mo = __shfl_xor(m, off);
      float so = __shfl_xor(ssum, off);
      int ao = __shfl_xor(arg, off);
      combine(m, ssum, arg, mo, so, ao);
    }
    if (lane == 0)
      redPack[wave] = make_float4(m, ssum, __int_as_float(arg), 0.f);
    barrier_lds();  // B4: reductions ready; rem reads fenced from writes

    // ====== phase F: final combine, q + slot-0/1 prefetch, shift-remove ==
    {
      float4 rp = redPack[lane & 15];
      float M = rp.x, S = rp.y;
      int Af = __float_as_int(rp.z);
      dpp_combine<0xB1>(M, S, Af);
      dpp_combine<0x4E>(M, S, Af);
      dpp_combine<0x141>(M, S, Af);
      dpp_combine<0x128>(M, S, Af);
      A = Af;
      total += -logf(S);  // chosen logit == M => log_p[act] = -log S
      // prefetch next q row (every thread knows A; load crosses B5)
      const uint4* qr = (const uint4*)(qsb + (size_t)A * kE);
      qa = qr[2 * t];
      qb_ = qr[2 * t + 1];
      // next-step slot-0/1 K+V prefetch via locally patched sorted rem:
      // next[j] = old[j] < A ? old[j] : old[j+1]  (shift-left semantics)
      int Rn = R - 1;
      pjn0 = (g < Rn) ? ((pr0 < A) ? pr0 : pr1) : -1;
      pjn1 = (g + 128 < Rn) ? ((pr2 < A) ? pr2 : pr3) : -1;
      if (pjn0 >= 0) {
        kb0 = ((const uint4*)(kqb + (size_t)pjn0 * kE))[t];
        vb0 = ((const uint4*)(vqb + (size_t)pjn0 * kE))[t];
      }
      if (pjn1 >= 0) {
        kb1 = ((const uint4*)(kqb + (size_t)pjn1 * kE))[t];
        vb1 = ((const uint4*)(vqb + (size_t)pjn1 * kE))[t];
      }
      // sorted shift-remove: shift condition is local (id >= A)
      if (tid < R - 1 && myv >= A) rem[tid] = nxt;
    }
    barrier_lds();  // B5: rem updated for next step
  }
  if (tid == 0) out[b] = total;
}

// ---------------------------------------------------------------------------
extern "C" void kernel_launch(void* const* d_in, const int* in_sizes, int n_in,
                              void* d_out, int out_size, void* d_ws,
                              size_t ws_size, hipStream_t stream) {
  const float* ne = (const float*)d_in[0];
  const float* ge = (const float*)d_in[1];
  const float* Wqkv = (const float*)d_in[2];
  const float* bqkv = (const float*)d_in[3];
  const float* Wfix = (const float*)d_in[4];
  const float* bfix = (const float*)d_in[5];
  const float* Wstep = (const float*)d_in[6];
  const float* bstep = (const float*)d_in[7];
  const float* Wmlp = (const float*)d_in[8];
  const float* bmlp = (const float*)d_in[9];
  float* out = (float*)d_out;

  size_t nkv = (size_t)kB * kN * kE;  // bytes per fp8 tensor
  unsigned char* kq = (unsigned char*)d_ws;
  unsigned char* vq = kq + nkv;
  unsigned char* lkq = vq + nkv;
  __half* qstep = (__half*)(lkq + nkv);  // 2*nkv bytes
  float* qbase = (float*)(qstep + nkv);  // 64 KB

  qkv_kernel<<<dim3(kB, (kN + 15) / 16), 384, 0, stream>>>(ne, Wqkv, bqkv, kq,
                                                           vq, lkq);
  qbase_kernel<<<kB, kE, 0, stream>>>(ne, ge, Wfix, bfix, Wstep, bstep, qbase);
  qstep_kernel<<<dim3(kB, kN / 8), 128, 0, stream>>>(ne, Wstep, qbase, qstep);
  rollout_kernel<<<kB, 1024, 0, stream>>>(Wmlp, bmlp, kq, vq, lkq, qstep, out);
}